// Round 2
// baseline (600.303 us; speedup 1.0000x reference)
//
#include <hip/hip_runtime.h>

#define NTOK 49
#define DIM  128
#define NH   4
#define HD   32
#define NWIN 8192
#define NWM  64

typedef short short8 __attribute__((ext_vector_type(8)));
typedef float f32x4  __attribute__((ext_vector_type(4)));

#if __has_builtin(__builtin_amdgcn_cvt_pk_bf16_f32)
typedef __bf16 bf16x2_t __attribute__((ext_vector_type(2)));
__device__ __forceinline__ unsigned pk2(float a, float b) {
  bf16x2_t r = __builtin_amdgcn_cvt_pk_bf16_f32(a, b);
  return __builtin_bit_cast(unsigned, r);
}
#else
__device__ __forceinline__ unsigned bfr(float f) {
  unsigned u = __builtin_bit_cast(unsigned, f);
  return (u + 0x7FFFu + ((u >> 16) & 1u)) >> 16;
}
__device__ __forceinline__ unsigned pk2(float a, float b) {
  return bfr(a) | (bfr(b) << 16);
}
#endif
__device__ __forceinline__ short f2bf(float f) { return (short)(pk2(f, 0.f) & 0xFFFFu); }

union S8 { short8 v; unsigned u[4]; };

// One prep kernel: bf16 weights + fused (bias+mask) table in softmax-coalesced layout
//   bmv[wm][h][mt][r][nt][lane]  (lane = quad*16+l16; m=mt*16+(lane>>4)*4+r, n=nt*16+(lane&15))
__global__ void prep(const float* __restrict__ qkv_w, const float* __restrict__ proj_w,
                     const float* __restrict__ attn_mask, const float* __restrict__ rpb_table,
                     const int* __restrict__ rpb_index,
                     short* __restrict__ wq, short* __restrict__ wp,
                     float* __restrict__ bmv, int do_bm) {
  int i = blockIdx.x * 256 + threadIdx.x;
  if (i < 3 * DIM * DIM) { wq[i] = f2bf(qkv_w[i]); return; }
  i -= 3 * DIM * DIM;
  if (i < DIM * DIM) { wp[i] = f2bf(proj_w[i]); return; }
  if (!do_bm) return;
  i -= DIM * DIM;
  if (i >= NWM * NH * 4096) return;
  int within = i & 4095;
  int wmh = i >> 12;
  int wm = wmh >> 2, h = wmh & 3;
  int lane = within & 63;
  int nt = (within >> 6) & 3;
  int r  = (within >> 8) & 3;
  int mt = within >> 10;
  int m = mt * 16 + (lane >> 4) * 4 + r;
  int n = nt * 16 + (lane & 15);
  float v = 0.f;
  if (m < NTOK && n < NTOK)
    v = rpb_table[rpb_index[m * NTOK + n] * NH + h] + attn_mask[(wm * NTOK + m) * NTOK + n];
  bmv[i] = v;
}

// LDS: 4 head regions of 10240 B = 40960 total -> 4 blocks/CU.
//   Per head: Q[64][40] (5120) | K[64][40] (5120)
//   After S reads Q/K fragments: Vt[32][72] (4608) overlays Q; P-half[64][40] overlays K.
//   Y[64][136] (17408) overlays everything (barrier-protected).
#define QK_S 40
#define VT_S 72
#define Y_S  136

template<bool USE_BM>
__global__ void __launch_bounds__(256, 4)
swin_attn(const float* __restrict__ x,
          const short* __restrict__ wq, const short* __restrict__ wp,
          const float* __restrict__ qkv_b, const float* __restrict__ proj_b,
          const float* __restrict__ bm,
          const int* __restrict__ rpb_index, const float* __restrict__ rpb_table,
          const float* __restrict__ attn_mask,
          float* __restrict__ out) {
  __shared__ __align__(16) char smem[40960];
  const int w    = blockIdx.x;
  const int tid  = threadIdx.x;
  const int h    = tid >> 6;          // wave id == head id
  const int lane = tid & 63;
  const int l16  = lane & 15;
  const int quad = lane >> 4;

  short* qh = (short*)(smem + h * 10240);
  short* kh = qh + 64 * QK_S;
  short* vth = qh;                    // overlays Q after aQ preload
  short* ph  = kh;                    // overlays K after bK preload
  short* yb  = (short*)smem;          // overlays all head regions

  // ---- phase 0: x A-fragments (global -> regs, fp32 -> bf16 packed) ----
  S8 af[4][4];
  const float* xw = x + (size_t)w * (NTOK * DIM);
  #pragma unroll
  for (int mt = 0; mt < 4; ++mt) {
    int row = mt * 16 + l16; if (row > 48) row = 48;   // clamp pad rows
    #pragma unroll
    for (int ks = 0; ks < 4; ++ks) {
      const f32x4* p = (const f32x4*)(xw + row * DIM + ks * 32 + quad * 8);
      f32x4 f0 = p[0], f1 = p[1];
      af[mt][ks].u[0] = pk2(f0[0], f0[1]);
      af[mt][ks].u[1] = pk2(f0[2], f0[3]);
      af[mt][ks].u[2] = pk2(f1[0], f1[1]);
      af[mt][ks].u[3] = pk2(f1[2], f1[3]);
    }
  }

  const float scale = 0.17677669529663687f;  // 32^-0.5, folded into Q

  // ---- phase 1a: V chunk -> bf16 regs (C-layout, packed r-pairs) ----
  unsigned vpk[2][4][2];   // [nt][mt][pair]
  #pragma unroll
  for (int nt = 0; nt < 2; ++nt) {
    f32x4 acc[4];
    #pragma unroll
    for (int mt = 0; mt < 4; ++mt) { f32x4 z = {0.f,0.f,0.f,0.f}; acc[mt] = z; }
    const short* bw = wq + (2 * DIM + h * HD + nt * 16 + l16) * DIM;
    #pragma unroll
    for (int ks = 0; ks < 4; ++ks) {
      short8 b = *(const short8*)(bw + ks * 32 + quad * 8);
      #pragma unroll
      for (int mt = 0; mt < 4; ++mt)
        acc[mt] = __builtin_amdgcn_mfma_f32_16x16x32_bf16(af[mt][ks].v, b, acc[mt], 0, 0, 0);
    }
    float bias = qkv_b[2 * DIM + h * HD + nt * 16 + l16];
    #pragma unroll
    for (int mt = 0; mt < 4; ++mt) {
      vpk[nt][mt][0] = pk2(acc[mt][0] + bias, acc[mt][1] + bias);
      vpk[nt][mt][1] = pk2(acc[mt][2] + bias, acc[mt][3] + bias);
    }
  }

  // ---- phase 1b: Q chunk -> LDS [tok][hd], scale folded ----
  #pragma unroll
  for (int nt = 0; nt < 2; ++nt) {
    f32x4 acc[4];
    #pragma unroll
    for (int mt = 0; mt < 4; ++mt) { f32x4 z = {0.f,0.f,0.f,0.f}; acc[mt] = z; }
    const short* bw = wq + (h * HD + nt * 16 + l16) * DIM;
    #pragma unroll
    for (int ks = 0; ks < 4; ++ks) {
      short8 b = *(const short8*)(bw + ks * 32 + quad * 8);
      #pragma unroll
      for (int mt = 0; mt < 4; ++mt)
        acc[mt] = __builtin_amdgcn_mfma_f32_16x16x32_bf16(af[mt][ks].v, b, acc[mt], 0, 0, 0);
    }
    float bias = qkv_b[h * HD + nt * 16 + l16];
    #pragma unroll
    for (int mt = 0; mt < 4; ++mt)
      #pragma unroll
      for (int r = 0; r < 4; ++r)
        qh[(mt * 16 + quad * 4 + r) * QK_S + nt * 16 + l16] = f2bf((acc[mt][r] + bias) * scale);
  }

  // ---- phase 1c: K chunk -> LDS [tok][hd] ----
  #pragma unroll
  for (int nt = 0; nt < 2; ++nt) {
    f32x4 acc[4];
    #pragma unroll
    for (int mt = 0; mt < 4; ++mt) { f32x4 z = {0.f,0.f,0.f,0.f}; acc[mt] = z; }
    const short* bw = wq + (DIM + h * HD + nt * 16 + l16) * DIM;
    #pragma unroll
    for (int ks = 0; ks < 4; ++ks) {
      short8 b = *(const short8*)(bw + ks * 32 + quad * 8);
      #pragma unroll
      for (int mt = 0; mt < 4; ++mt)
        acc[mt] = __builtin_amdgcn_mfma_f32_16x16x32_bf16(af[mt][ks].v, b, acc[mt], 0, 0, 0);
    }
    float bias = qkv_b[DIM + h * HD + nt * 16 + l16];
    #pragma unroll
    for (int mt = 0; mt < 4; ++mt)
      #pragma unroll
      for (int r = 0; r < 4; ++r)
        kh[(mt * 16 + quad * 4 + r) * QK_S + nt * 16 + l16] = f2bf(acc[mt][r] + bias);
  }
  // af dead here.

  // ---- preload all Q/K fragments, then recycle their LDS ----
  short8 aQ[4], bK[4];
  #pragma unroll
  for (int mt = 0; mt < 4; ++mt) aQ[mt] = *(const short8*)(qh + (mt * 16 + l16) * QK_S + quad * 8);
  #pragma unroll
  for (int nt = 0; nt < 4; ++nt) bK[nt] = *(const short8*)(kh + (nt * 16 + l16) * QK_S + quad * 8);

  // Vt (bf16 regs -> LDS over Q region): Vt[d][tok], packed b32 writes
  #pragma unroll
  for (int nt = 0; nt < 2; ++nt)
    #pragma unroll
    for (int mt = 0; mt < 4; ++mt) {
      int d = nt * 16 + l16;
      int t0 = mt * 16 + quad * 4;
      *(unsigned*)(vth + d * VT_S + t0)     = vpk[nt][mt][0];
      *(unsigned*)(vth + d * VT_S + t0 + 2) = vpk[nt][mt][1];
    }
  short8 bV[2][2];   // [kt][dt]
  #pragma unroll
  for (int kt = 0; kt < 2; ++kt)
    #pragma unroll
    for (int dt = 0; dt < 2; ++dt)
      bV[kt][dt] = *(const short8*)(vth + (dt * 16 + l16) * VT_S + kt * 32 + quad * 8);

  // ---- per-mt pipeline: S -> softmax (no max-sub, P pre-normalized) -> PV ----
  const int wm = w & (NWM - 1);
  const float* bmh = USE_BM ? bm + ((size_t)(wm * NH + h) << 12) : nullptr;
  f32x4 y0[4], y1[4];
  #pragma unroll
  for (int mt = 0; mt < 4; ++mt) {
    f32x4 s[4];
    #pragma unroll
    for (int nt = 0; nt < 4; ++nt) { f32x4 z = {0.f,0.f,0.f,0.f}; s[nt] = z; }
    #pragma unroll
    for (int nt = 0; nt < 4; ++nt)
      s[nt] = __builtin_amdgcn_mfma_f32_16x16x32_bf16(aQ[mt], bK[nt], s[nt], 0, 0, 0);

    float p2[4], p3[4];
    #pragma unroll
    for (int r = 0; r < 4; ++r) {
      int m = mt * 16 + quad * 4 + r;
      float pv[4]; float t = 0.f;
      #pragma unroll
      for (int nt = 0; nt < 4; ++nt) {
        int n = nt * 16 + l16;
        float v = s[nt][r];
        if (n >= NTOK) v = -1e30f;
        else if (USE_BM) v += bmh[((mt * 4 + r) * 4 + nt) * 64 + lane];
        else if (m < NTOK) v += rpb_table[rpb_index[m * NTOK + n] * NH + h]
                              + attn_mask[(wm * NTOK + m) * NTOK + n];
        float p = __expf(v);
        pv[nt] = p; t += p;
      }
      t += __shfl_xor(t, 1, 16);
      t += __shfl_xor(t, 2, 16);
      t += __shfl_xor(t, 4, 16);
      t += __shfl_xor(t, 8, 16);
      float rinv = 1.0f / t;
      ph[m * QK_S + l16]      = f2bf(pv[0] * rinv);
      ph[m * QK_S + 16 + l16] = f2bf(pv[1] * rinv);
      p2[r] = pv[2] * rinv; p3[r] = pv[3] * rinv;
    }
    short8 aP = *(const short8*)(ph + (mt * 16 + l16) * QK_S + quad * 8);
    f32x4 z = {0.f,0.f,0.f,0.f};
    y0[mt] = __builtin_amdgcn_mfma_f32_16x16x32_bf16(aP, bV[0][0], z, 0, 0, 0);
    y1[mt] = __builtin_amdgcn_mfma_f32_16x16x32_bf16(aP, bV[0][1], z, 0, 0, 0);
    #pragma unroll
    for (int r = 0; r < 4; ++r) {
      int m = mt * 16 + quad * 4 + r;
      ph[m * QK_S + l16]      = f2bf(p2[r]);
      ph[m * QK_S + 16 + l16] = f2bf(p3[r]);
    }
    aP = *(const short8*)(ph + (mt * 16 + l16) * QK_S + quad * 8);
    y0[mt] = __builtin_amdgcn_mfma_f32_16x16x32_bf16(aP, bV[1][0], y0[mt], 0, 0, 0);
    y1[mt] = __builtin_amdgcn_mfma_f32_16x16x32_bf16(aP, bV[1][1], y1[mt], 0, 0, 0);
  }

  __syncthreads();   // all waves done with their head regions before Y overlays
  #pragma unroll
  for (int mt = 0; mt < 4; ++mt)
    #pragma unroll
    for (int r = 0; r < 4; ++r) {
      int m = mt * 16 + quad * 4 + r;
      yb[m * Y_S + h * HD + l16]      = f2bf(y0[mt][r]);
      yb[m * Y_S + h * HD + 16 + l16] = f2bf(y1[mt][r]);
    }
  __syncthreads();   // Y complete before proj reads cross-head

  // ---- proj: out = Y proj_w^T + proj_b; wave h -> out cols [32h, 32h+32) ----
  {
    const int o0 = h * 32;
    f32x4 oa[2][4];
    #pragma unroll
    for (int nt = 0; nt < 2; ++nt)
      #pragma unroll
      for (int mt = 0; mt < 4; ++mt) { f32x4 z = {0.f,0.f,0.f,0.f}; oa[nt][mt] = z; }
    #pragma unroll
    for (int ks = 0; ks < 4; ++ks) {
      short8 aY[4];
      #pragma unroll
      for (int mt = 0; mt < 4; ++mt) aY[mt] = *(const short8*)(yb + (mt * 16 + l16) * Y_S + ks * 32 + quad * 8);
      short8 b0 = *(const short8*)(wp + (o0 + l16) * DIM + ks * 32 + quad * 8);
      short8 b1 = *(const short8*)(wp + (o0 + 16 + l16) * DIM + ks * 32 + quad * 8);
      #pragma unroll
      for (int mt = 0; mt < 4; ++mt) {
        oa[0][mt] = __builtin_amdgcn_mfma_f32_16x16x32_bf16(aY[mt], b0, oa[0][mt], 0, 0, 0);
        oa[1][mt] = __builtin_amdgcn_mfma_f32_16x16x32_bf16(aY[mt], b1, oa[1][mt], 0, 0, 0);
      }
    }
    float pb0 = proj_b[o0 + l16], pb1 = proj_b[o0 + 16 + l16];
    float* ow = out + (size_t)w * (NTOK * DIM);
    #pragma unroll
    for (int nt = 0; nt < 2; ++nt) {
      float pb = nt ? pb1 : pb0;
      #pragma unroll
      for (int mt = 0; mt < 4; ++mt)
        #pragma unroll
        for (int r = 0; r < 4; ++r) {
          int m = mt * 16 + quad * 4 + r;
          if (m < NTOK) ow[m * DIM + o0 + nt * 16 + l16] = (nt ? oa[1][mt][r] : oa[0][mt][r]) + pb;
        }
    }
  }
}

extern "C" void kernel_launch(void* const* d_in, const int* in_sizes, int n_in,
                              void* d_out, int out_size, void* d_ws, size_t ws_size,
                              hipStream_t stream) {
  const float* x         = (const float*)d_in[0];
  const float* attn_mask = (const float*)d_in[1];
  const float* qkv_w     = (const float*)d_in[2];
  const float* qkv_b     = (const float*)d_in[3];
  const float* proj_w    = (const float*)d_in[4];
  const float* proj_b    = (const float*)d_in[5];
  const float* rpb_table = (const float*)d_in[6];
  const int*   rpb_index = (const int*)d_in[7];
  float* out = (float*)d_out;

  short* wq = (short*)d_ws;                          // 49152 bf16
  short* wp = wq + 3 * DIM * DIM;                    // 16384 bf16
  float* bmv = (float*)((char*)d_ws + 131072);       // [64][4][4][4][4][64] f32 = 4 MB
  size_t need = 131072 + (size_t)NWM * NH * 4096 * sizeof(float);
  bool use_bm = ws_size >= need;

  prep<<<4352, 256, 0, stream>>>(qkv_w, proj_w, attn_mask, rpb_table, rpb_index,
                                 wq, wp, bmv, use_bm ? 1 : 0);
  if (use_bm)
    swin_attn<true><<<NWIN, 256, 0, stream>>>(x, wq, wp, qkv_b, proj_b, bmv,
                                              rpb_index, rpb_table, attn_mask, out);
  else
    swin_attn<false><<<NWIN, 256, 0, stream>>>(x, wq, wp, qkv_b, proj_b, nullptr,
                                               rpb_index, rpb_table, attn_mask, out);
}